// Round 7
// baseline (350.873 us; speedup 1.0000x reference)
//
#include <hip/hip_runtime.h>

#define NN 8192
#define HD 512
#define NL 3
#define CAP 128
#define LN_EPS 1e-5f

typedef _Float16 f16;
typedef _Float16 f16x8 __attribute__((ext_vector_type(8)));
typedef _Float16 f16x4 __attribute__((ext_vector_type(4)));
typedef _Float16 f16x2 __attribute__((ext_vector_type(2)));
typedef float f32x4 __attribute__((ext_vector_type(4)));

__device__ __forceinline__ unsigned short f16_bits(f16 h) {
  union { f16 h; unsigned short u; } x; x.h = h; return x.u;
}
__device__ __forceinline__ f16 bits_f16(unsigned short u) {
  union { unsigned short u; f16 h; } x; x.u = u; return x.h;
}

// ---------------------------------------------------------------------------
// k_prep: blocks [0,NN) do the adjacency pass; blocks [NN, NN+273*NL) do all
// weight preprocessing (merged so the two independent jobs share one dispatch).
//
// Adjacency part: one HBM pass over dense A (f32, symmetric, zero diag,
// entries >= 0), row staged in registers (8 float4/thread).  Emits ELL:
// packed u32 = (f16(w)<<16)|col, self-loop w=1 appended (diag always 0),
// padded with w=0 to a multiple of 8.  deg=rowsum+1 -> dinv=deg^-1/2.
// Fused: xs[r] = x0[r]*dinv[r] (f16).
//
// Weights part (per l): bx<256: WlT[n][m]=(Wc@Wm)[m][n] f16 (2 m-rows/block);
// bx==256: bl = conv_b@Wm + mlp_b; bx>256 (l==0): lwT[n][k]=lin_w[k][n] f16.
__global__ __launch_bounds__(256) void k_prep(const float* __restrict__ A,
                                              const float* __restrict__ x0,
                                              const float* __restrict__ convw,
                                              const float* __restrict__ mlpw,
                                              const float* __restrict__ convb,
                                              const float* __restrict__ mlpb,
                                              const float* __restrict__ lw,
                                              unsigned* __restrict__ ell,
                                              int* __restrict__ nnz8,
                                              float* __restrict__ dinv,
                                              f16* __restrict__ xs,
                                              f16* __restrict__ WlT,
                                              float* __restrict__ bl,
                                              f16* __restrict__ lwT) {
  const int b = blockIdx.x;
  const int t = threadIdx.x;

  if (b >= NN) {                       // ---------------- weight-prep blocks
    const int wl = b - NN;
    const int l = wl / 273;
    const int bx = wl % 273;
    if (bx < 256) {
      const int m0 = bx * 2;
      const float* Wc = convw + (size_t)l * HD * HD;
      const float* Wm = mlpw + (size_t)l * HD * HD;
      f16* o = WlT + (size_t)l * HD * HD;
      float a00 = 0.f, a01 = 0.f, a10 = 0.f, a11 = 0.f;
      const float* wc0 = Wc + (size_t)m0 * HD;
      const float* wc1 = Wc + (size_t)(m0 + 1) * HD;
      for (int k = 0; k < HD; k++) {
        const float w0 = Wm[(size_t)k * HD + t];
        const float w1 = Wm[(size_t)k * HD + t + 256];
        const float c0 = wc0[k];
        const float c1 = wc1[k];
        a00 = fmaf(c0, w0, a00);
        a01 = fmaf(c0, w1, a01);
        a10 = fmaf(c1, w0, a10);
        a11 = fmaf(c1, w1, a11);
      }
      o[(size_t)t * HD + m0] = (f16)a00;
      o[(size_t)(t + 256) * HD + m0] = (f16)a01;
      o[(size_t)t * HD + m0 + 1] = (f16)a10;
      o[(size_t)(t + 256) * HD + m0 + 1] = (f16)a11;
    } else if (bx == 256) {
      const float* Wm = mlpw + (size_t)l * HD * HD;
      float acc0 = mlpb[l * HD + t];
      float acc1 = mlpb[l * HD + t + 256];
      for (int k = 0; k < HD; k++) {
        const float cb = convb[l * HD + k];
        acc0 = fmaf(cb, Wm[(size_t)k * HD + t], acc0);
        acc1 = fmaf(cb, Wm[(size_t)k * HD + t + 256], acc1);
      }
      bl[l * HD + t] = acc0;
      bl[l * HD + t + 256] = acc1;
    } else if (l == 0) {
      const int base = (bx - 257) * 16384;   // 16 blocks cover 512*512
      #pragma unroll 4
      for (int j = 0; j < 64; j++) {
        const int idx = base + j * 256 + t;
        const int k = idx >> 9, n = idx & 511;
        lwT[(size_t)n * HD + k] = (f16)lw[idx];
      }
    }
    return;
  }

  // ------------------------------------------------------ adjacency blocks
  __shared__ int wtot[4];
  __shared__ float wsum[4];
  __shared__ float sdinv;
  const int r = b;
  const int lane = t & 63;
  const int wv = t >> 6;
  const float4* ar = (const float4*)(A + (size_t)r * NN);
  unsigned* er = ell + (size_t)r * CAP;

  float4 v[8];
  int c = 0;
  float s = 0.f;
  #pragma unroll
  for (int i = 0; i < 8; i++) {
    v[i] = ar[t + i * 256];
    c += (v[i].x > 0.f) + (v[i].y > 0.f) + (v[i].z > 0.f) + (v[i].w > 0.f);
    s += v[i].x + v[i].y + v[i].z + v[i].w;   // entries are >= 0
  }
  int inc = c;
  #pragma unroll
  for (int d = 1; d < 64; d <<= 1) {
    int vv = __shfl_up(inc, d);
    if (lane >= d) inc += vv;
  }
  float ss = s;
  #pragma unroll
  for (int m = 1; m < 64; m <<= 1) ss += __shfl_xor(ss, m);
  if (lane == 63) wtot[wv] = inc;
  if (lane == 0) wsum[wv] = ss;
  __syncthreads();
  int base = inc - c;                       // exclusive within wave
  for (int w = 0; w < wv; w++) base += wtot[w];

  int o = base;
  #pragma unroll
  for (int i = 0; i < 8; i++) {
    float vals[4] = {v[i].x, v[i].y, v[i].z, v[i].w};
    #pragma unroll
    for (int q = 0; q < 4; q++) {
      float val = vals[q];
      if (val > 0.f) {
        if (o < CAP) er[o] = ((unsigned)f16_bits((f16)val) << 16) | (unsigned)((t + i * 256) * 4 + q);
        o++;
      }
    }
  }
  if (t == 255) {
    int ne = wtot[0] + wtot[1] + wtot[2] + wtot[3];
    if (ne < CAP) er[ne] = (0x3C00u << 16) | (unsigned)r;   // self-loop w=1.0
    int ne1 = ne + 1; if (ne1 > CAP) ne1 = CAP;
    int n8 = (ne1 + 7) & ~7;
    for (int k = ne1; k < n8; k++) er[k] = (unsigned)r;     // w = +0.0 pad
    nnz8[r] = n8;
    float deg = wsum[0] + wsum[1] + wsum[2] + wsum[3] + 1.f;
    float di = rsqrtf(deg);
    dinv[r] = di;
    sdinv = di;
  }
  __syncthreads();
  {
    const float di = sdinv;
    const float2 xv = ((const float2*)(x0 + (size_t)r * HD))[t];
    f16x2 o2 = {(f16)(xv.x * di), (f16)(xv.y * di)};
    ((f16x2*)(xs + (size_t)r * HD))[t] = o2;
  }
}

// ---------------------------------------------------------------------------
// Fused layer: {ELL SpMM -> y (XOR-swizzled LDS)} -> {GEMM + bias + LN + ReLU
// + optional dinv}.  256 blocks x 512 threads; block owns 32 output rows.
// Phase 1: 4 rows/wave, per edge one f16x8 gather/lane (xs rows, L2/L3).
// Phase 2: the proven M=32 shape -- 8 waves in 2 rowgroups x 4 colgroups,
// A-fragments from LDS (swizzle (row&7)<<3 on the f16 element index breaks
// the 16-way bank conflict of row-major [32][512]).
__global__ __launch_bounds__(512) void k_layer(const unsigned* __restrict__ ell,
                                               const int* __restrict__ nnz8,
                                               const float* __restrict__ dinv,
                                               const f16* __restrict__ xs,
                                               const f16* __restrict__ WT,
                                               const float* __restrict__ bias,
                                               const float* __restrict__ g,
                                               const float* __restrict__ bb,
                                               const float* __restrict__ dscale,
                                               f16* __restrict__ outp) {
  __shared__ __attribute__((aligned(16))) f16 ylds[32 * HD];   // 32 KB
  __shared__ float red[32][4][2];
  const int t = threadIdx.x;
  const int lane = t & 63;
  const int w = t >> 6;
  const int m0 = blockIdx.x * 32;

  // ---- phase 1: SpMM for rows m0 + w*4 .. +3 ----
  {
    const int wu = __builtin_amdgcn_readfirstlane(w);
    for (int i = 0; i < 4; i++) {
      const int r = m0 + wu * 4 + i;
      const uint4* er = (const uint4*)(ell + (size_t)r * CAP);
      const int ne = nnz8[r];
      float acc[8] = {0.f, 0.f, 0.f, 0.f, 0.f, 0.f, 0.f, 0.f};
      for (int e8 = 0; e8 < (ne >> 3); e8++) {
        const uint4 ea = er[e8 * 2];
        const uint4 eb = er[e8 * 2 + 1];
        unsigned wvs[8] = {ea.x, ea.y, ea.z, ea.w, eb.x, eb.y, eb.z, eb.w};
        f16x8 xv[8];
        #pragma unroll
        for (int q = 0; q < 8; q++)
          xv[q] = *(const f16x8*)(xs + (size_t)(wvs[q] & 0xFFFFu) * HD + lane * 8);
        #pragma unroll
        for (int q = 0; q < 8; q++) {
          const float fw = (float)bits_f16((unsigned short)(wvs[q] >> 16));
          #pragma unroll
          for (int j = 0; j < 8; j++)
            acc[j] = fmaf(fw, (float)xv[q][j], acc[j]);
        }
      }
      const float s = dinv[r];
      f16x8 o;
      #pragma unroll
      for (int j = 0; j < 8; j++) o[j] = (f16)(acc[j] * s);
      const int lr = wu * 4 + i;
      const int ce = (lane * 8) ^ ((lr & 7) << 3);     // swizzled write
      *(f16x8*)(&ylds[lr * HD + ce]) = o;
    }
  }
  __syncthreads();

  // ---- phase 2: GEMM + bias + LN + ReLU (+ dinv) ----
  const int wm = w >> 2;          // 0..1 rowgroup
  const int wn = w & 3;           // 0..3 colgroup
  const int rl = lane & 15, kghi = lane >> 4;
  const int lr = wm * 16 + rl;
  const f16* bP = WT + (size_t)(wn * 128 + rl) * HD + kghi * 8;

  f32x4 acc[8];
  #pragma unroll
  for (int j = 0; j < 8; j++) { f32x4 z = {0.f, 0.f, 0.f, 0.f}; acc[j] = z; }

  #pragma unroll 2
  for (int ks = 0; ks < HD; ks += 32) {
    const int ce = (ks + kghi * 8) ^ ((lr & 7) << 3);  // swizzled read
    const f16x8 af = *(const f16x8*)(&ylds[lr * HD + ce]);
    #pragma unroll
    for (int j = 0; j < 8; j++) {
      const f16x8 bf = *(const f16x8*)(bP + (size_t)j * 16 * HD + ks);
      acc[j] = __builtin_amdgcn_mfma_f32_16x16x32_f16(af, bf, acc[j], 0, 0, 0);
    }
  }

  const int cg = kghi, cl = rl;
  float av[8][4];
  #pragma unroll
  for (int j = 0; j < 8; j++) {
    const float bv = bias[wn * 128 + j * 16 + cl];
    #pragma unroll
    for (int r = 0; r < 4; r++) av[j][r] = acc[j][r] + bv;
  }
  #pragma unroll
  for (int r = 0; r < 4; r++) {
    float s = 0.f, sq = 0.f;
    #pragma unroll
    for (int j = 0; j < 8; j++) { s += av[j][r]; sq += av[j][r] * av[j][r]; }
    #pragma unroll
    for (int m = 1; m < 16; m <<= 1) { s += __shfl_xor(s, m); sq += __shfl_xor(sq, m); }
    if (cl == 0) {
      red[wm * 16 + cg * 4 + r][wn][0] = s;
      red[wm * 16 + cg * 4 + r][wn][1] = sq;
    }
  }
  __syncthreads();
  #pragma unroll
  for (int r = 0; r < 4; r++) {
    const int rb = wm * 16 + cg * 4 + r;
    float s = 0.f, sq = 0.f;
    #pragma unroll
    for (int q = 0; q < 4; q++) { s += red[rb][q][0]; sq += red[rb][q][1]; }
    const float mu = s * (1.f / HD);
    const float rs = rsqrtf(sq * (1.f / HD) - mu * mu + LN_EPS);
    const int row = m0 + rb;
    const float dsc = dscale ? dscale[row] : 1.f;
    #pragma unroll
    for (int j = 0; j < 8; j++) {
      const int col = wn * 128 + j * 16 + cl;
      const float val = fmaxf((av[j][r] - mu) * rs * g[col] + bb[col], 0.f) * dsc;
      outp[(size_t)row * HD + col] = (f16)val;
    }
  }
}

// ---------------------------------------------------------------------------
// Direct-from-L2 MFMA GEMM (final linear): C[M,512] = A[M,512] @ BT^T + bias.
__global__ __launch_bounds__(256) void k_gemm_direct(const f16* __restrict__ A,
                                                     const f16* __restrict__ BT,
                                                     float* __restrict__ C,
                                                     const float* __restrict__ bias) {
  const int t = threadIdx.x;
  const int lane = t & 63;
  const int wave = t >> 6;
  const int wm = wave >> 1, wn = wave & 1;
  const int m0 = blockIdx.x * 128, n0 = blockIdx.y * 128;
  const int rl = lane & 15, kg = (lane >> 4) * 8;

  const f16* aP[4];
  const f16* bP[4];
  #pragma unroll
  for (int i = 0; i < 4; i++)
    aP[i] = A + (size_t)(m0 + wm * 64 + i * 16 + rl) * HD + kg;
  #pragma unroll
  for (int j = 0; j < 4; j++)
    bP[j] = BT + (size_t)(n0 + wn * 64 + j * 16 + rl) * HD + kg;

  f32x4 acc[4][4];
  #pragma unroll
  for (int i = 0; i < 4; i++)
    #pragma unroll
    for (int j = 0; j < 4; j++) {
      f32x4 z = {0.f, 0.f, 0.f, 0.f};
      acc[i][j] = z;
    }

  #pragma unroll 4
  for (int ks = 0; ks < HD; ks += 32) {
    f16x8 af[4], bf[4];
    #pragma unroll
    for (int i = 0; i < 4; i++) af[i] = *(const f16x8*)(aP[i] + ks);
    #pragma unroll
    for (int j = 0; j < 4; j++) bf[j] = *(const f16x8*)(bP[j] + ks);
    #pragma unroll
    for (int i = 0; i < 4; i++)
      #pragma unroll
      for (int j = 0; j < 4; j++)
        acc[i][j] = __builtin_amdgcn_mfma_f32_16x16x32_f16(af[i], bf[j], acc[i][j], 0, 0, 0);
  }

  const int cg = lane >> 4, cl = lane & 15;
  #pragma unroll
  for (int i = 0; i < 4; i++) {
    #pragma unroll
    for (int j = 0; j < 4; j++) {
      const int col = n0 + wn * 64 + j * 16 + cl;
      const float bv = bias ? bias[col] : 0.f;
      #pragma unroll
      for (int rr = 0; rr < 4; rr++) {
        const int row = m0 + wm * 64 + i * 16 + cg * 4 + rr;
        C[(size_t)row * HD + col] = acc[i][j][rr] + bv;
      }
    }
  }
}

// ---------------------------------------------------------------------------
extern "C" void kernel_launch(void* const* d_in, const int* in_sizes, int n_in,
                              void* d_out, int out_size, void* d_ws, size_t ws_size,
                              hipStream_t stream) {
  const float* node_feat = (const float*)d_in[0];
  const float* adj       = (const float*)d_in[1];
  const float* conv_w    = (const float*)d_in[2];
  const float* conv_b    = (const float*)d_in[3];
  const float* mlp_w     = (const float*)d_in[4];
  const float* mlp_b     = (const float*)d_in[5];
  const float* ln_g      = (const float*)d_in[6];
  const float* ln_b      = (const float*)d_in[7];
  const float* lin_w     = (const float*)d_in[8];
  const float* lin_b     = (const float*)d_in[9];
  float* out = (float*)d_out;

  // workspace carve (~21 MB)
  char* p = (char*)d_ws;
  unsigned* ell = (unsigned*)p; p += (size_t)NN * CAP * 4;   // 4 MB
  int* nnz8  = (int*)p;   p += (size_t)NN * 4;
  float* dinv = (float*)p; p += (size_t)NN * 4;
  f16* xsA   = (f16*)p;   p += (size_t)NN * HD * 2;          // 8 MB
  f16* xsB   = (f16*)p;   p += (size_t)NN * HD * 2;          // 8 MB
  f16* WlT   = (f16*)p;   p += (size_t)NL * HD * HD * 2;
  f16* lwT   = (f16*)p;   p += (size_t)HD * HD * 2;
  float* bl  = (float*)p; p += (size_t)NL * HD * 4;

  k_prep<<<NN + 273 * NL, 256, 0, stream>>>(adj, node_feat, conv_w, mlp_w,
                                            conv_b, mlp_b, lin_w,
                                            ell, nnz8, dinv, xsA, WlT, bl, lwT);

  f16* xcur = xsA;
  for (int l = 0; l < NL; l++) {
    f16* nxt = (xcur == xsA) ? xsB : xsA;
    k_layer<<<NN / 32, 512, 0, stream>>>(ell, nnz8, dinv, xcur,
                                         WlT + (size_t)l * HD * HD, bl + l * HD,
                                         ln_g + l * HD, ln_b + l * HD,
                                         (l < 2) ? dinv : nullptr, nxt);
    xcur = nxt;
  }
  k_gemm_direct<<<dim3(64, 4), 256, 0, stream>>>(xcur, lwT, out, lin_b);
}

// Round 8
// 332.481 us; speedup vs baseline: 1.0553x; 1.0553x over previous
//
#include <hip/hip_runtime.h>

#define NN 8192
#define HD 512
#define NL 3
#define CAP 128
#define NWB (273 * NL)
#define LN_EPS 1e-5f

typedef _Float16 f16;
typedef _Float16 f16x8 __attribute__((ext_vector_type(8)));
typedef _Float16 f16x4 __attribute__((ext_vector_type(4)));
typedef _Float16 f16x2 __attribute__((ext_vector_type(2)));
typedef float f32x4 __attribute__((ext_vector_type(4)));

__device__ __forceinline__ unsigned short f16_bits(f16 h) {
  union { f16 h; unsigned short u; } x; x.h = h; return x.u;
}
__device__ __forceinline__ f16 bits_f16(unsigned short u) {
  union { unsigned short u; f16 h; } x; x.u = u; return x.h;
}

// ---------------------------------------------------------------------------
// k_prep: blocks [0, NWB) do weight preprocessing (placed FIRST so their
// latency-bound loops hide under the adjacency pass); blocks [NWB, NWB+NN)
// do the adjacency pass, one row each.
//
// Adjacency: one pass over dense A (f32, symmetric, zero diag, entries>=0).
// KEY: each block sweeps its 32KB-aligned row starting at float4 offset
// (r*5)&2047 -- co-resident blocks otherwise march in lockstep through
// identical low address bits (same HBM channels / L3 slices / L2 sets at
// every instant), which capped the whole kernel at ~1.6 TB/s regardless of
// cache hits.  Rotation de-phases the streams.  Two passes (count+scan,
// reload+emit); reloads are L1/L2-hot.  Emits ELL u32 = (f16(w)<<16)|col,
// self-loop w=1 appended (diag always 0), w=0 pad to multiple of 8.
// deg=rowsum+1 -> dinv=deg^-1/2.  Fused: xs[r] = x0[r]*dinv[r] (f16).
__global__ __launch_bounds__(256) void k_prep(const float* __restrict__ A,
                                              const float* __restrict__ x0,
                                              const float* __restrict__ convw,
                                              const float* __restrict__ mlpw,
                                              const float* __restrict__ convb,
                                              const float* __restrict__ mlpb,
                                              const float* __restrict__ lw,
                                              unsigned* __restrict__ ell,
                                              int* __restrict__ nnz8,
                                              float* __restrict__ dinv,
                                              f16* __restrict__ xs,
                                              f16* __restrict__ WlT,
                                              float* __restrict__ bl,
                                              f16* __restrict__ lwT) {
  const int b = blockIdx.x;
  const int t = threadIdx.x;

  if (b < NWB) {                       // ---------------- weight-prep blocks
    const int l = b / 273;
    const int bx = b % 273;
    if (bx < 256) {
      const int m0 = bx * 2;
      const float* Wc = convw + (size_t)l * HD * HD;
      const float* Wm = mlpw + (size_t)l * HD * HD;
      f16* o = WlT + (size_t)l * HD * HD;
      float a00 = 0.f, a01 = 0.f, a10 = 0.f, a11 = 0.f;
      const float* wc0 = Wc + (size_t)m0 * HD;
      const float* wc1 = Wc + (size_t)(m0 + 1) * HD;
      for (int k = 0; k < HD; k++) {
        const float w0 = Wm[(size_t)k * HD + t];
        const float w1 = Wm[(size_t)k * HD + t + 256];
        const float c0 = wc0[k];
        const float c1 = wc1[k];
        a00 = fmaf(c0, w0, a00);
        a01 = fmaf(c0, w1, a01);
        a10 = fmaf(c1, w0, a10);
        a11 = fmaf(c1, w1, a11);
      }
      o[(size_t)t * HD + m0] = (f16)a00;
      o[(size_t)(t + 256) * HD + m0] = (f16)a01;
      o[(size_t)t * HD + m0 + 1] = (f16)a10;
      o[(size_t)(t + 256) * HD + m0 + 1] = (f16)a11;
    } else if (bx == 256) {
      const float* Wm = mlpw + (size_t)l * HD * HD;
      float acc0 = mlpb[l * HD + t];
      float acc1 = mlpb[l * HD + t + 256];
      for (int k = 0; k < HD; k++) {
        const float cb = convb[l * HD + k];
        acc0 = fmaf(cb, Wm[(size_t)k * HD + t], acc0);
        acc1 = fmaf(cb, Wm[(size_t)k * HD + t + 256], acc1);
      }
      bl[l * HD + t] = acc0;
      bl[l * HD + t + 256] = acc1;
    } else if (l == 0) {
      const int base = (bx - 257) * 16384;   // 16 blocks cover 512*512
      #pragma unroll 4
      for (int j = 0; j < 64; j++) {
        const int idx = base + j * 256 + t;
        const int k = idx >> 9, n = idx & 511;
        lwT[(size_t)n * HD + k] = (f16)lw[idx];
      }
    }
    return;
  }

  // ------------------------------------------------------ adjacency blocks
  __shared__ int wtot[4];
  __shared__ float wsum[4];
  __shared__ float sdinv;
  const int r = b - NWB;
  const int lane = t & 63;
  const int wv = t >> 6;
  const float4* ar = (const float4*)(A + (size_t)r * NN);
  unsigned* er = ell + (size_t)r * CAP;
  const int rot = (r * 5) & 2047;          // per-row de-phasing

  // pass 1: count + sum
  int c = 0;
  float s = 0.f;
  #pragma unroll
  for (int i = 0; i < 8; i++) {
    const int f = (t + i * 256 + rot) & 2047;
    const float4 v = ar[f];
    c += (v.x > 0.f) + (v.y > 0.f) + (v.z > 0.f) + (v.w > 0.f);
    s += v.x + v.y + v.z + v.w;            // entries are >= 0
  }
  int inc = c;
  #pragma unroll
  for (int d = 1; d < 64; d <<= 1) {
    int vv = __shfl_up(inc, d);
    if (lane >= d) inc += vv;
  }
  float ss = s;
  #pragma unroll
  for (int m = 1; m < 64; m <<= 1) ss += __shfl_xor(ss, m);
  if (lane == 63) wtot[wv] = inc;
  if (lane == 0) wsum[wv] = ss;
  __syncthreads();
  int base = inc - c;                      // exclusive within wave
  for (int w = 0; w < wv; w++) base += wtot[w];

  // pass 2: reload (L1/L2-hot) + emit
  int o = base;
  #pragma unroll
  for (int i = 0; i < 8; i++) {
    const int f = (t + i * 256 + rot) & 2047;
    const float4 v = ar[f];
    float vals[4] = {v.x, v.y, v.z, v.w};
    #pragma unroll
    for (int q = 0; q < 4; q++) {
      float val = vals[q];
      if (val > 0.f) {
        if (o < CAP) er[o] = ((unsigned)f16_bits((f16)val) << 16) | (unsigned)(f * 4 + q);
        o++;
      }
    }
  }
  if (t == 255) {
    int ne = wtot[0] + wtot[1] + wtot[2] + wtot[3];
    if (ne < CAP) er[ne] = (0x3C00u << 16) | (unsigned)r;   // self-loop w=1.0
    int ne1 = ne + 1; if (ne1 > CAP) ne1 = CAP;
    int n8 = (ne1 + 7) & ~7;
    for (int k = ne1; k < n8; k++) er[k] = (unsigned)r;     // w = +0.0 pad
    nnz8[r] = n8;
    float deg = wsum[0] + wsum[1] + wsum[2] + wsum[3] + 1.f;
    float di = rsqrtf(deg);
    dinv[r] = di;
    sdinv = di;
  }
  __syncthreads();
  {
    const float di = sdinv;
    const float2 xv = ((const float2*)(x0 + (size_t)r * HD))[t];
    f16x2 o2 = {(f16)(xv.x * di), (f16)(xv.y * di)};
    ((f16x2*)(xs + (size_t)r * HD))[t] = o2;
  }
}

// ---------------------------------------------------------------------------
// Column-chunked SpMM: y[r] = dinv[r] * sum_e w_e * xs[col_e].
// chunk = bid&3 (NOT bid>>11): co-resident blocks then cover all four 256B
// column windows of the 1KB xs rows -> full channel/slice coverage.
// 4 waves/block, one row each; edges via uniform uint4 s_loads; per edge per
// lane: one f16x2 gather + 2 fma.
__global__ __launch_bounds__(256) void k_spmm(const unsigned* __restrict__ ell,
                                              const int* __restrict__ nnz8,
                                              const float* __restrict__ dinv,
                                              const f16* __restrict__ xs,
                                              f16* __restrict__ y) {
  const int bid = blockIdx.x;              // 0..8191
  const int chunk = bid & 3;
  const int rb = bid >> 2;
  const int r = __builtin_amdgcn_readfirstlane(rb * 4 + (threadIdx.x >> 6));
  const int lane = threadIdx.x & 63;
  const int c0 = chunk * 128 + lane * 2;
  const uint4* er = (const uint4*)(ell + (size_t)r * CAP);
  const int ne = nnz8[r];
  const f16* xc = xs + c0;
  float a0 = 0.f, a1 = 0.f;
  for (int e8 = 0; e8 < (ne >> 3); e8++) {
    const uint4 ea = er[e8 * 2];
    const uint4 eb = er[e8 * 2 + 1];
    unsigned wv[8] = {ea.x, ea.y, ea.z, ea.w, eb.x, eb.y, eb.z, eb.w};
    f16x2 xv[8];
    #pragma unroll
    for (int q = 0; q < 8; q++)
      xv[q] = *(const f16x2*)(xc + (size_t)(wv[q] & 0xFFFFu) * HD);
    #pragma unroll
    for (int q = 0; q < 8; q++) {
      const float fw = (float)bits_f16((unsigned short)(wv[q] >> 16));
      a0 = fmaf(fw, (float)xv[q][0], a0);
      a1 = fmaf(fw, (float)xv[q][1], a1);
    }
  }
  const float s = dinv[r];
  f16x2 o = {(f16)(a0 * s), (f16)(a1 * s)};
  *(f16x2*)(y + (size_t)r * HD + c0) = o;
}

// ---------------------------------------------------------------------------
// Fused GEMM + bias + LayerNorm + ReLU + optional dinv scale, f16 out.
// M=32 x N=512 per block (256 blocks = full GPU), 512 threads = 8 waves in
// 2 rowgroups x 4 colgroups; per-CU W streaming = 512 KB.
__global__ __launch_bounds__(512) void k_gemm_ln(const f16* __restrict__ y,
                                                 const f16* __restrict__ WT,
                                                 const float* __restrict__ bias,
                                                 const float* __restrict__ g,
                                                 const float* __restrict__ bb,
                                                 const float* __restrict__ dscale,
                                                 f16* __restrict__ outp) {
  __shared__ float red[32][4][2];
  const int t = threadIdx.x;
  const int lane = t & 63;
  const int w = t >> 6;
  const int wm = w >> 2;          // 0..1 rowgroup
  const int wn = w & 3;           // 0..3 colgroup
  const int m0 = blockIdx.x * 32;
  const int rl = lane & 15, kg = (lane >> 4) * 8;
  const f16* aP = y + (size_t)(m0 + wm * 16 + rl) * HD + kg;
  const f16* bP = WT + (size_t)(wn * 128 + rl) * HD + kg;

  f32x4 acc[8];
  #pragma unroll
  for (int j = 0; j < 8; j++) { f32x4 z = {0.f, 0.f, 0.f, 0.f}; acc[j] = z; }

  #pragma unroll 2
  for (int ks = 0; ks < HD; ks += 32) {
    const f16x8 af = *(const f16x8*)(aP + ks);
    #pragma unroll
    for (int j = 0; j < 8; j++) {
      const f16x8 bf = *(const f16x8*)(bP + (size_t)j * 16 * HD + ks);
      acc[j] = __builtin_amdgcn_mfma_f32_16x16x32_f16(af, bf, acc[j], 0, 0, 0);
    }
  }

  const int cg = lane >> 4, cl = lane & 15;
  float av[8][4];
  #pragma unroll
  for (int j = 0; j < 8; j++) {
    const float bv = bias[wn * 128 + j * 16 + cl];
    #pragma unroll
    for (int r = 0; r < 4; r++) av[j][r] = acc[j][r] + bv;
  }
  #pragma unroll
  for (int r = 0; r < 4; r++) {
    float s = 0.f, sq = 0.f;
    #pragma unroll
    for (int j = 0; j < 8; j++) { s += av[j][r]; sq += av[j][r] * av[j][r]; }
    #pragma unroll
    for (int m = 1; m < 16; m <<= 1) { s += __shfl_xor(s, m); sq += __shfl_xor(sq, m); }
    if (cl == 0) {
      red[wm * 16 + cg * 4 + r][wn][0] = s;
      red[wm * 16 + cg * 4 + r][wn][1] = sq;
    }
  }
  __syncthreads();
  #pragma unroll
  for (int r = 0; r < 4; r++) {
    const int rb = wm * 16 + cg * 4 + r;
    float s = 0.f, sq = 0.f;
    #pragma unroll
    for (int q = 0; q < 4; q++) { s += red[rb][q][0]; sq += red[rb][q][1]; }
    const float mu = s * (1.f / HD);
    const float rs = rsqrtf(sq * (1.f / HD) - mu * mu + LN_EPS);
    const int row = m0 + rb;
    const float dsc = dscale ? dscale[row] : 1.f;
    #pragma unroll
    for (int j = 0; j < 8; j++) {
      const int col = wn * 128 + j * 16 + cl;
      const float val = fmaxf((av[j][r] - mu) * rs * g[col] + bb[col], 0.f) * dsc;
      outp[(size_t)row * HD + col] = (f16)val;
    }
  }
}

// ---------------------------------------------------------------------------
// Direct-from-L2 MFMA GEMM (final linear): C[M,512] = A[M,512] @ BT^T + bias.
__global__ __launch_bounds__(256) void k_gemm_direct(const f16* __restrict__ A,
                                                     const f16* __restrict__ BT,
                                                     float* __restrict__ C,
                                                     const float* __restrict__ bias) {
  const int t = threadIdx.x;
  const int lane = t & 63;
  const int wave = t >> 6;
  const int wm = wave >> 1, wn = wave & 1;
  const int m0 = blockIdx.x * 128, n0 = blockIdx.y * 128;
  const int rl = lane & 15, kg = (lane >> 4) * 8;

  const f16* aP[4];
  const f16* bP[4];
  #pragma unroll
  for (int i = 0; i < 4; i++)
    aP[i] = A + (size_t)(m0 + wm * 64 + i * 16 + rl) * HD + kg;
  #pragma unroll
  for (int j = 0; j < 4; j++)
    bP[j] = BT + (size_t)(n0 + wn * 64 + j * 16 + rl) * HD + kg;

  f32x4 acc[4][4];
  #pragma unroll
  for (int i = 0; i < 4; i++)
    #pragma unroll
    for (int j = 0; j < 4; j++) {
      f32x4 z = {0.f, 0.f, 0.f, 0.f};
      acc[i][j] = z;
    }

  #pragma unroll 4
  for (int ks = 0; ks < HD; ks += 32) {
    f16x8 af[4], bf[4];
    #pragma unroll
    for (int i = 0; i < 4; i++) af[i] = *(const f16x8*)(aP[i] + ks);
    #pragma unroll
    for (int j = 0; j < 4; j++) bf[j] = *(const f16x8*)(bP[j] + ks);
    #pragma unroll
    for (int i = 0; i < 4; i++)
      #pragma unroll
      for (int j = 0; j < 4; j++)
        acc[i][j] = __builtin_amdgcn_mfma_f32_16x16x32_f16(af[i], bf[j], acc[i][j], 0, 0, 0);
  }

  const int cg = lane >> 4, cl = lane & 15;
  #pragma unroll
  for (int i = 0; i < 4; i++) {
    #pragma unroll
    for (int j = 0; j < 4; j++) {
      const int col = n0 + wn * 64 + j * 16 + cl;
      const float bv = bias ? bias[col] : 0.f;
      #pragma unroll
      for (int rr = 0; rr < 4; rr++) {
        const int row = m0 + wm * 64 + i * 16 + cg * 4 + rr;
        C[(size_t)row * HD + col] = acc[i][j][rr] + bv;
      }
    }
  }
}

// ---------------------------------------------------------------------------
extern "C" void kernel_launch(void* const* d_in, const int* in_sizes, int n_in,
                              void* d_out, int out_size, void* d_ws, size_t ws_size,
                              hipStream_t stream) {
  const float* node_feat = (const float*)d_in[0];
  const float* adj       = (const float*)d_in[1];
  const float* conv_w    = (const float*)d_in[2];
  const float* conv_b    = (const float*)d_in[3];
  const float* mlp_w     = (const float*)d_in[4];
  const float* mlp_b     = (const float*)d_in[5];
  const float* ln_g      = (const float*)d_in[6];
  const float* ln_b      = (const float*)d_in[7];
  const float* lin_w     = (const float*)d_in[8];
  const float* lin_b     = (const float*)d_in[9];
  float* out = (float*)d_out;

  // workspace carve (~30 MB)
  char* p = (char*)d_ws;
  unsigned* ell = (unsigned*)p; p += (size_t)NN * CAP * 4;   // 4 MB
  int* nnz8  = (int*)p;   p += (size_t)NN * 4;
  float* dinv = (float*)p; p += (size_t)NN * 4;
  f16* xsA   = (f16*)p;   p += (size_t)NN * HD * 2;          // 8 MB
  f16* xsB   = (f16*)p;   p += (size_t)NN * HD * 2;          // 8 MB
  f16* ybuf  = (f16*)p;   p += (size_t)NN * HD * 2;          // 8 MB
  f16* WlT   = (f16*)p;   p += (size_t)NL * HD * HD * 2;
  f16* lwT   = (f16*)p;   p += (size_t)HD * HD * 2;
  float* bl  = (float*)p; p += (size_t)NL * HD * 4;

  k_prep<<<NWB + NN, 256, 0, stream>>>(adj, node_feat, conv_w, mlp_w,
                                       conv_b, mlp_b, lin_w,
                                       ell, nnz8, dinv, xsA, WlT, bl, lwT);

  f16* xcur = xsA;
  for (int l = 0; l < NL; l++) {
    k_spmm<<<NN, 256, 0, stream>>>(ell, nnz8, dinv, xcur, ybuf);
    f16* nxt = (xcur == xsA) ? xsB : xsA;
    k_gemm_ln<<<NN / 32, 512, 0, stream>>>(ybuf, WlT + (size_t)l * HD * HD,
                                           bl + l * HD, ln_g + l * HD, ln_b + l * HD,
                                           (l < 2) ? dinv : nullptr, nxt);
    xcur = nxt;
  }
  k_gemm_direct<<<dim3(64, 4), 256, 0, stream>>>(xcur, lwT, out, lin_b);
}

// Round 9
// 329.290 us; speedup vs baseline: 1.0655x; 1.0097x over previous
//
#include <hip/hip_runtime.h>

#define NN 8192
#define HD 512
#define NL 3
#define CAPQ 48               // ELL capacity per row-quarter (mean nnz/quarter ~17)
#define CAPR (4 * CAPQ)       // 192 u32 per row
#define NWB (273 * NL)
#define LN_EPS 1e-5f

typedef _Float16 f16;
typedef _Float16 f16x8 __attribute__((ext_vector_type(8)));
typedef _Float16 f16x4 __attribute__((ext_vector_type(4)));
typedef _Float16 f16x2 __attribute__((ext_vector_type(2)));
typedef float f32x4 __attribute__((ext_vector_type(4)));

__device__ __forceinline__ unsigned short f16_bits(f16 h) {
  union { f16 h; unsigned short u; } x; x.h = h; return x.u;
}
__device__ __forceinline__ f16 bits_f16(unsigned short u) {
  union { unsigned short u; f16 h; } x; x.u = u; return x.h;
}

// ---------------------------------------------------------------------------
// k_prep: blocks [0,NWB) = weight prep (first, hides under the big pass);
// blocks [NWB, NWB+4*NN) = adjacency pass, ONE 8KB ROW-QUARTER PER BLOCK.
// sb = b-NWB; r = sb>>2, seg = sb&3 -> consecutive blocks read consecutive
// 8KB (the m13 linear-streaming partition).  Each block: 2 float4/thread in
// registers (single read), wave scan + LDS combine, emit segment-local ELL
// (u32 = f16(w)<<16 | col) at ell[r*192 + seg*48], self-loop w=1 appended by
// the owning segment (seg == r>>11; diag of A is always 0), w=0 pad to
// multiple of 8, count in nnz8q[4r+seg], weight-sum in psum[4r+seg].
__global__ __launch_bounds__(256) void k_prep(const float* __restrict__ A,
                                              const float* __restrict__ convw,
                                              const float* __restrict__ mlpw,
                                              const float* __restrict__ convb,
                                              const float* __restrict__ mlpb,
                                              const float* __restrict__ lw,
                                              unsigned* __restrict__ ell,
                                              int* __restrict__ nnz8q,
                                              float* __restrict__ psum,
                                              f16* __restrict__ WlT,
                                              float* __restrict__ bl,
                                              f16* __restrict__ lwT) {
  const int b = blockIdx.x;
  const int t = threadIdx.x;

  if (b < NWB) {                       // ---------------- weight-prep blocks
    const int l = b / 273;
    const int bx = b % 273;
    if (bx < 256) {
      const int m0 = bx * 2;
      const float* Wc = convw + (size_t)l * HD * HD;
      const float* Wm = mlpw + (size_t)l * HD * HD;
      f16* o = WlT + (size_t)l * HD * HD;
      float a00 = 0.f, a01 = 0.f, a10 = 0.f, a11 = 0.f;
      const float* wc0 = Wc + (size_t)m0 * HD;
      const float* wc1 = Wc + (size_t)(m0 + 1) * HD;
      for (int k = 0; k < HD; k++) {
        const float w0 = Wm[(size_t)k * HD + t];
        const float w1 = Wm[(size_t)k * HD + t + 256];
        const float c0 = wc0[k];
        const float c1 = wc1[k];
        a00 = fmaf(c0, w0, a00);
        a01 = fmaf(c0, w1, a01);
        a10 = fmaf(c1, w0, a10);
        a11 = fmaf(c1, w1, a11);
      }
      o[(size_t)t * HD + m0] = (f16)a00;
      o[(size_t)(t + 256) * HD + m0] = (f16)a01;
      o[(size_t)t * HD + m0 + 1] = (f16)a10;
      o[(size_t)(t + 256) * HD + m0 + 1] = (f16)a11;
    } else if (bx == 256) {
      const float* Wm = mlpw + (size_t)l * HD * HD;
      float acc0 = mlpb[l * HD + t];
      float acc1 = mlpb[l * HD + t + 256];
      for (int k = 0; k < HD; k++) {
        const float cb = convb[l * HD + k];
        acc0 = fmaf(cb, Wm[(size_t)k * HD + t], acc0);
        acc1 = fmaf(cb, Wm[(size_t)k * HD + t + 256], acc1);
      }
      bl[l * HD + t] = acc0;
      bl[l * HD + t + 256] = acc1;
    } else if (l == 0) {
      const int base = (bx - 257) * 16384;   // 16 blocks cover 512*512
      #pragma unroll 4
      for (int j = 0; j < 64; j++) {
        const int idx = base + j * 256 + t;
        const int k = idx >> 9, n = idx & 511;
        lwT[(size_t)n * HD + k] = (f16)lw[idx];
      }
    }
    return;
  }

  // ------------------------------------------------- row-quarter blocks
  __shared__ int wtot[4];
  __shared__ float wsum[4];
  const int sb = b - NWB;
  const int r = sb >> 2;
  const int seg = sb & 3;
  const int lane = t & 63;
  const int wv = t >> 6;
  const float4* aseg = (const float4*)(A + (size_t)r * NN + seg * 2048);
  unsigned* er = ell + (size_t)r * CAPR + seg * CAPQ;

  const float4 v0 = aseg[t];
  const float4 v1 = aseg[t + 256];
  int c = (v0.x > 0.f) + (v0.y > 0.f) + (v0.z > 0.f) + (v0.w > 0.f) +
          (v1.x > 0.f) + (v1.y > 0.f) + (v1.z > 0.f) + (v1.w > 0.f);
  float s = v0.x + v0.y + v0.z + v0.w + v1.x + v1.y + v1.z + v1.w;  // >= 0

  int inc = c;
  #pragma unroll
  for (int d = 1; d < 64; d <<= 1) {
    int vv = __shfl_up(inc, d);
    if (lane >= d) inc += vv;
  }
  float ss = s;
  #pragma unroll
  for (int m = 1; m < 64; m <<= 1) ss += __shfl_xor(ss, m);
  if (lane == 63) wtot[wv] = inc;
  if (lane == 0) wsum[wv] = ss;
  __syncthreads();
  int base = inc - c;                      // exclusive within wave
  for (int w = 0; w < wv; w++) base += wtot[w];

  int o = base;
  const int cb0 = seg * 2048 + t * 4;          // cols of v0
  const int cb1 = seg * 2048 + (t + 256) * 4;  // cols of v1
  {
    float vals[4] = {v0.x, v0.y, v0.z, v0.w};
    #pragma unroll
    for (int q = 0; q < 4; q++) {
      if (vals[q] > 0.f) {
        if (o < CAPQ) er[o] = ((unsigned)f16_bits((f16)vals[q]) << 16) | (unsigned)(cb0 + q);
        o++;
      }
    }
  }
  {
    float vals[4] = {v1.x, v1.y, v1.z, v1.w};
    #pragma unroll
    for (int q = 0; q < 4; q++) {
      if (vals[q] > 0.f) {
        if (o < CAPQ) er[o] = ((unsigned)f16_bits((f16)vals[q]) << 16) | (unsigned)(cb1 + q);
        o++;
      }
    }
  }
  if (t == 255) {
    int ne = wtot[0] + wtot[1] + wtot[2] + wtot[3];
    if (ne > CAPQ) ne = CAPQ;
    const bool own = (seg == (r >> 11));           // self-loop lives here
    if (own && ne < CAPQ) { er[ne] = (0x3C00u << 16) | (unsigned)r; ne++; }
    const int n8 = (ne + 7) & ~7;
    for (int k = ne; k < n8; k++) er[k] = (unsigned)r;   // w = +0.0 pad
    nnz8q[r * 4 + seg] = n8;
    psum[r * 4 + seg] = wsum[0] + wsum[1] + wsum[2] + wsum[3];
  }
}

// ---------------------------------------------------------------------------
// k_deg: reduce the 4 segment sums -> dinv = (rowsum+1)^-1/2; fused x-scale
// xs[r] = x0[r] * dinv[r] (f16).  2048 blocks x 4 waves, one row per wave.
__global__ __launch_bounds__(256) void k_deg(const float* __restrict__ psum,
                                             const float* __restrict__ x0,
                                             float* __restrict__ dinv,
                                             f16* __restrict__ xs) {
  const int r = blockIdx.x * 4 + (threadIdx.x >> 6);
  const int lane = threadIdx.x & 63;
  const float4 ps = *(const float4*)(psum + (size_t)r * 4);   // wave-uniform
  const float di = rsqrtf(ps.x + ps.y + ps.z + ps.w + 1.f);
  if (lane == 0) dinv[r] = di;
  const float4* xr = (const float4*)(x0 + (size_t)r * HD);
  const float4 a = xr[lane * 2];
  const float4 bq = xr[lane * 2 + 1];
  f16x8 o = {(f16)(a.x * di), (f16)(a.y * di), (f16)(a.z * di), (f16)(a.w * di),
             (f16)(bq.x * di), (f16)(bq.y * di), (f16)(bq.z * di), (f16)(bq.w * di)};
  *(f16x8*)(xs + (size_t)r * HD + lane * 8) = o;
}

// ---------------------------------------------------------------------------
// Column-chunked SpMM over segmented ELL: y[r] = dinv[r] * sum w_e*xs[col_e].
// chunk = bid&3 (co-resident blocks cover all four 256B column windows).
// 4 waves/block, one row each; edge words via uniform s_loads; per edge per
// lane: one f16x2 gather + 2 fma.
__global__ __launch_bounds__(256) void k_spmm(const unsigned* __restrict__ ell,
                                              const int* __restrict__ nnz8q,
                                              const float* __restrict__ dinv,
                                              const f16* __restrict__ xs,
                                              f16* __restrict__ y) {
  const int bid = blockIdx.x;              // 0..8191
  const int chunk = bid & 3;
  const int rb = bid >> 2;
  const int r = __builtin_amdgcn_readfirstlane(rb * 4 + (threadIdx.x >> 6));
  const int lane = threadIdx.x & 63;
  const int c0 = chunk * 128 + lane * 2;
  const unsigned* erow = ell + (size_t)r * CAPR;
  const int4 nn = *(const int4*)(nnz8q + (size_t)r * 4);
  const int ne8s[4] = {nn.x >> 3, nn.y >> 3, nn.z >> 3, nn.w >> 3};
  const f16* xc = xs + c0;
  float a0 = 0.f, a1 = 0.f;
  #pragma unroll
  for (int seg = 0; seg < 4; seg++) {
    const uint4* er = (const uint4*)(erow + seg * CAPQ);
    const int ne8 = ne8s[seg];
    for (int e8 = 0; e8 < ne8; e8++) {
      const uint4 ea = er[e8 * 2];
      const uint4 eb = er[e8 * 2 + 1];
      unsigned wv[8] = {ea.x, ea.y, ea.z, ea.w, eb.x, eb.y, eb.z, eb.w};
      f16x2 xv[8];
      #pragma unroll
      for (int q = 0; q < 8; q++)
        xv[q] = *(const f16x2*)(xc + (size_t)(wv[q] & 0xFFFFu) * HD);
      #pragma unroll
      for (int q = 0; q < 8; q++) {
        const float fw = (float)bits_f16((unsigned short)(wv[q] >> 16));
        a0 = fmaf(fw, (float)xv[q][0], a0);
        a1 = fmaf(fw, (float)xv[q][1], a1);
      }
    }
  }
  const float s = dinv[r];
  f16x2 o = {(f16)(a0 * s), (f16)(a1 * s)};
  *(f16x2*)(y + (size_t)r * HD + c0) = o;
}

// ---------------------------------------------------------------------------
// Fused GEMM + bias + LayerNorm + ReLU + optional dinv scale, f16 out.
// M=32 x N=512 per block (256 blocks), 512 threads = 8 waves (2 rowgroups x
// 4 colgroups); per-CU W streaming = 512 KB.
__global__ __launch_bounds__(512) void k_gemm_ln(const f16* __restrict__ y,
                                                 const f16* __restrict__ WT,
                                                 const float* __restrict__ bias,
                                                 const float* __restrict__ g,
                                                 const float* __restrict__ bb,
                                                 const float* __restrict__ dscale,
                                                 f16* __restrict__ outp) {
  __shared__ float red[32][4][2];
  const int t = threadIdx.x;
  const int lane = t & 63;
  const int w = t >> 6;
  const int wm = w >> 2;          // 0..1 rowgroup
  const int wn = w & 3;           // 0..3 colgroup
  const int m0 = blockIdx.x * 32;
  const int rl = lane & 15, kg = (lane >> 4) * 8;
  const f16* aP = y + (size_t)(m0 + wm * 16 + rl) * HD + kg;
  const f16* bP = WT + (size_t)(wn * 128 + rl) * HD + kg;

  f32x4 acc[8];
  #pragma unroll
  for (int j = 0; j < 8; j++) { f32x4 z = {0.f, 0.f, 0.f, 0.f}; acc[j] = z; }

  #pragma unroll 2
  for (int ks = 0; ks < HD; ks += 32) {
    const f16x8 af = *(const f16x8*)(aP + ks);
    #pragma unroll
    for (int j = 0; j < 8; j++) {
      const f16x8 bf = *(const f16x8*)(bP + (size_t)j * 16 * HD + ks);
      acc[j] = __builtin_amdgcn_mfma_f32_16x16x32_f16(af, bf, acc[j], 0, 0, 0);
    }
  }

  const int cg = lane >> 4, cl = lane & 15;
  float av[8][4];
  #pragma unroll
  for (int j = 0; j < 8; j++) {
    const float bv = bias[wn * 128 + j * 16 + cl];
    #pragma unroll
    for (int r = 0; r < 4; r++) av[j][r] = acc[j][r] + bv;
  }
  #pragma unroll
  for (int r = 0; r < 4; r++) {
    float s = 0.f, sq = 0.f;
    #pragma unroll
    for (int j = 0; j < 8; j++) { s += av[j][r]; sq += av[j][r] * av[j][r]; }
    #pragma unroll
    for (int m = 1; m < 16; m <<= 1) { s += __shfl_xor(s, m); sq += __shfl_xor(sq, m); }
    if (cl == 0) {
      red[wm * 16 + cg * 4 + r][wn][0] = s;
      red[wm * 16 + cg * 4 + r][wn][1] = sq;
    }
  }
  __syncthreads();
  #pragma unroll
  for (int r = 0; r < 4; r++) {
    const int rb = wm * 16 + cg * 4 + r;
    float s = 0.f, sq = 0.f;
    #pragma unroll
    for (int q = 0; q < 4; q++) { s += red[rb][q][0]; sq += red[rb][q][1]; }
    const float mu = s * (1.f / HD);
    const float rs = rsqrtf(sq * (1.f / HD) - mu * mu + LN_EPS);
    const int row = m0 + rb;
    const float dsc = dscale ? dscale[row] : 1.f;
    #pragma unroll
    for (int j = 0; j < 8; j++) {
      const int col = wn * 128 + j * 16 + cl;
      const float val = fmaxf((av[j][r] - mu) * rs * g[col] + bb[col], 0.f) * dsc;
      outp[(size_t)row * HD + col] = (f16)val;
    }
  }
}

// ---------------------------------------------------------------------------
// Direct-from-L2 MFMA GEMM (final linear): C[M,512] = A[M,512] @ BT^T + bias.
__global__ __launch_bounds__(256) void k_gemm_direct(const f16* __restrict__ A,
                                                     const f16* __restrict__ BT,
                                                     float* __restrict__ C,
                                                     const float* __restrict__ bias) {
  const int t = threadIdx.x;
  const int lane = t & 63;
  const int wave = t >> 6;
  const int wm = wave >> 1, wn = wave & 1;
  const int m0 = blockIdx.x * 128, n0 = blockIdx.y * 128;
  const int rl = lane & 15, kg = (lane >> 4) * 8;

  const f16* aP[4];
  const f16* bP[4];
  #pragma unroll
  for (int i = 0; i < 4; i++)
    aP[i] = A + (size_t)(m0 + wm * 64 + i * 16 + rl) * HD + kg;
  #pragma unroll
  for (int j = 0; j < 4; j++)
    bP[j] = BT + (size_t)(n0 + wn * 64 + j * 16 + rl) * HD + kg;

  f32x4 acc[4][4];
  #pragma unroll
  for (int i = 0; i < 4; i++)
    #pragma unroll
    for (int j = 0; j < 4; j++) {
      f32x4 z = {0.f, 0.f, 0.f, 0.f};
      acc[i][j] = z;
    }

  #pragma unroll 4
  for (int ks = 0; ks < HD; ks += 32) {
    f16x8 af[4], bf[4];
    #pragma unroll
    for (int i = 0; i < 4; i++) af[i] = *(const f16x8*)(aP[i] + ks);
    #pragma unroll
    for (int j = 0; j < 4; j++) bf[j] = *(const f16x8*)(bP[j] + ks);
    #pragma unroll
    for (int i = 0; i < 4; i++)
      #pragma unroll
      for (int j = 0; j < 4; j++)
        acc[i][j] = __builtin_amdgcn_mfma_f32_16x16x32_f16(af[i], bf[j], acc[i][j], 0, 0, 0);
  }

  const int cg = lane >> 4, cl = lane & 15;
  #pragma unroll
  for (int i = 0; i < 4; i++) {
    #pragma unroll
    for (int j = 0; j < 4; j++) {
      const int col = n0 + wn * 64 + j * 16 + cl;
      const float bv = bias ? bias[col] : 0.f;
      #pragma unroll
      for (int rr = 0; rr < 4; rr++) {
        const int row = m0 + wm * 64 + i * 16 + cg * 4 + rr;
        C[(size_t)row * HD + col] = acc[i][j][rr] + bv;
      }
    }
  }
}

// ---------------------------------------------------------------------------
extern "C" void kernel_launch(void* const* d_in, const int* in_sizes, int n_in,
                              void* d_out, int out_size, void* d_ws, size_t ws_size,
                              hipStream_t stream) {
  const float* node_feat = (const float*)d_in[0];
  const float* adj       = (const float*)d_in[1];
  const float* conv_w    = (const float*)d_in[2];
  const float* conv_b    = (const float*)d_in[3];
  const float* mlp_w     = (const float*)d_in[4];
  const float* mlp_b     = (const float*)d_in[5];
  const float* ln_g      = (const float*)d_in[6];
  const float* ln_b      = (const float*)d_in[7];
  const float* lin_w     = (const float*)d_in[8];
  const float* lin_b     = (const float*)d_in[9];
  float* out = (float*)d_out;

  // workspace carve (~33 MB)
  char* p = (char*)d_ws;
  unsigned* ell = (unsigned*)p; p += (size_t)NN * CAPR * 4;  // 6 MB
  int* nnz8q = (int*)p;  p += (size_t)NN * 4 * 4;            // 128 KB
  float* psum = (float*)p; p += (size_t)NN * 4 * 4;          // 128 KB
  float* dinv = (float*)p; p += (size_t)NN * 4;
  f16* xsA   = (f16*)p;   p += (size_t)NN * HD * 2;          // 8 MB
  f16* xsB   = (f16*)p;   p += (size_t)NN * HD * 2;          // 8 MB
  f16* ybuf  = (f16*)p;   p += (size_t)NN * HD * 2;          // 8 MB
  f16* WlT   = (f16*)p;   p += (size_t)NL * HD * HD * 2;
  f16* lwT   = (f16*)p;   p += (size_t)HD * HD * 2;
  float* bl  = (float*)p; p += (size_t)NL * HD * 4;

  k_prep<<<NWB + 4 * NN, 256, 0, stream>>>(adj, conv_w, mlp_w, conv_b, mlp_b,
                                           lin_w, ell, nnz8q, psum, WlT, bl, lwT);
  k_deg<<<NN / 4, 256, 0, stream>>>(psum, node_feat, dinv, xsA);

  f16* xcur = xsA;
  for (int l = 0; l < NL; l++) {
    k_spmm<<<NN, 256, 0, stream>>>(ell, nnz8q, dinv, xcur, ybuf);
    f16* nxt = (xcur == xsA) ? xsB : xsA;
    k_gemm_ln<<<NN / 32, 512, 0, stream>>>(ybuf, WlT + (size_t)l * HD * HD,
                                           bl + l * HD, ln_g + l * HD, ln_b + l * HD,
                                           (l < 2) ? dinv : nullptr, nxt);
    xcur = nxt;
  }
  k_gemm_direct<<<dim3(64, 4), 256, 0, stream>>>(xcur, lwT, out, lin_b);
}